// Round 5
// baseline (560.567 us; speedup 1.0000x reference)
//
#include <hip/hip_runtime.h>

typedef unsigned short u16;
typedef unsigned int   u32;
typedef __attribute__((ext_vector_type(8))) short short8;
typedef __attribute__((ext_vector_type(4))) float f32x4;

#define IMG_BYTES  557568      /* 66*66*64*2 (padded bf16 image) */
#define WS_SCALE   0
#define WS_SHIFT   256
#define WS_PART    512         /* 16 groups * 128 floats = 8192 B */
#define WS_WA      8704        /* 3 * 110592 u16 = 663552 B */
#define WS_BNXP    672256      /* 64 * IMG_BYTES */
#define WS_HC      (WS_BNXP + 64*IMG_BYTES)          /* 4 buffers x 4*IMG_BYTES */
#define WS_CSTATE  (WS_HC + 16*IMG_BYTES)            /* 4*64*4096 f32 = 4 MiB */

__device__ __forceinline__ u16 f2b(float f){
  u32 x = __float_as_uint(f);
  return (u16)((x + 0x7fffu + ((x>>16)&1u)) >> 16);
}
__device__ __forceinline__ float sigm(float x){ return 1.f/(1.f+__expf(-x)); }
__device__ __forceinline__ float tanh_(float x){
  float e = __expf(2.f*fabsf(x));
  float t = 1.f - 2.f/(e+1.f);      /* inf-safe -> 1 */
  return copysignf(t, x);
}

/* ---- weight transform: f32 [O][C][3][3] -> coalesced bf16 blocks ----
   byte addr = j*221184 + (tap*2+cc)*12288 + frg*1024 + lane*16 + e*2
   element = w_j[och = frg*16 + (lane&15)][c = cc*32 + (lane>>4)*8 + e] at tap */
__global__ void k_wt(const float* __restrict__ c1, const float* __restrict__ c2h,
                     const float* __restrict__ h2h, u16* __restrict__ wA){
  int idx = blockIdx.x*256 + threadIdx.x;   /* 1296*256 = 331776 exact */
  int e = idx & 7;
  int lane = (idx >> 3) & 63;
  int rest = idx >> 9;
  int frg = rest % 12;  rest /= 12;
  int cc = rest & 1;    rest >>= 1;
  int tap = rest % 9;
  int j = rest / 9;
  int och = frg*16 + (lane & 15);
  int c = cc*32 + (lane >> 4)*8 + e;
  const float* src = (j==0) ? c1 : ((j==1) ? c2h : h2h);
  wA[idx] = f2b(src[(och*64 + c)*9 + tap]);
}

/* ---- BN partial sums: block (c, g) reduces imgs g*4..g*4+3 (f32 input) ---- */
__global__ void k_bnsum(const float* __restrict__ x, float* __restrict__ part){
  int c = blockIdx.x & 63, g = blockIdx.x >> 6;
  int tid = threadIdx.x, w = tid >> 6, lane = tid & 63;
  float s = 0.f, s2 = 0.f;
  for (int im = 0; im < 4; ++im){
    const float* base = x + (((size_t)((g*4+im)*64 + c)) << 12);
    #pragma unroll
    for (int it = 0; it < 4; ++it){
      float4 v = *(const float4*)(base + (((it<<8) + tid) << 2));
      s  += v.x + v.y + v.z + v.w;
      s2 += v.x*v.x + v.y*v.y + v.z*v.z + v.w*v.w;
    }
  }
  #pragma unroll
  for (int off = 32; off > 0; off >>= 1){
    s  += __shfl_down(s,  off);
    s2 += __shfl_down(s2, off);
  }
  __shared__ float red[8];
  if (lane == 0){ red[w] = s; red[4+w] = s2; }
  __syncthreads();
  if (tid == 0){
    float S  = red[0]+red[1]+red[2]+red[3];
    float S2 = red[4]+red[5]+red[6]+red[7];
    part[(g<<7) + c] = S;
    part[(g<<7) + 64 + c] = S2;
  }
}

/* ---- BN finalize: scale/shift per channel (f32 gamma/beta) ---- */
__global__ void k_bnfin(const float* __restrict__ part, const float* __restrict__ gamma,
                        const float* __restrict__ beta, float* __restrict__ scale,
                        float* __restrict__ shift){
  int c = threadIdx.x;
  float S = 0.f, S2 = 0.f;
  for (int g = 0; g < 16; ++g){ S += part[(g<<7)+c]; S2 += part[(g<<7)+64+c]; }
  const float inv = 1.f/262144.f;
  float mean = S*inv;
  float var  = S2*inv - mean*mean;
  float sc = gamma[c] * rsqrtf(var + 1e-5f);
  scale[c] = sc;
  shift[c] = beta[c] - mean*sc;
}

/* ---- BN apply + transpose f32 NCHW -> padded bf16 [img][66][66][64];
        writes halo rows/cols itself (no memset needed). grid 64*66 ---- */
__global__ void k_bnx(const float* __restrict__ x, const float* __restrict__ scale,
                      const float* __restrict__ shift, char* __restrict__ bnxp){
  int img = blockIdx.x / 66, rp = blockIdx.x % 66;
  int tid = threadIdx.x;
  char* dstrow = bnxp + (size_t)img*IMG_BYTES + (size_t)rp*8448;
  const uint4 z = {0,0,0,0};
  if (rp == 0 || rp == 65){
    for (int i = tid; i < 528; i += 256) ((uint4*)dstrow)[i] = z;
    return;
  }
  if (tid < 16)
    *(uint4*)(dstrow + (tid>>3)*(65*128) + (tid&7)*16) = z;   /* halo cols 0,65 */
  int r = rp - 1;
  int col = tid & 63, cq = tid >> 6;
  const float* xb = x + (((size_t)(img*64 + cq*16)) << 12) + (r<<6) + col;
  union { u16 u[16]; uint4 v[2]; } pk;
  #pragma unroll
  for (int i = 0; i < 16; ++i){
    int c = cq*16 + i;
    float vv = xb[((size_t)i) << 12];
    pk.u[i] = f2b(vv*scale[c] + shift[c]);
  }
  char* dst = dstrow + (size_t)(col + 1)*128 + cq*32;
  *(uint4*)dst = pk.v[0];
  *(uint4*)(dst+16) = pk.v[1];
}

/* ---- fused ConvLSTM step: 512 blocks = 4 img x 32 row-pairs x 4 och-groups.
        4 waves: wave (wr,ch) = row wr of pair, col-half ch, all 3 gate frags
        of its 16-och group. 2 blocks/CU -> 2 waves/SIMD. ---- */
__global__ __launch_bounds__(256, 2) void k_step(
    const char* __restrict__ bnxp,
    const char* __restrict__ cpad_s, const char* __restrict__ hpad_s,
    char* __restrict__ cpad_d, char* __restrict__ hpad_d,
    const char* __restrict__ wA, const float* __restrict__ b1,
    float* __restrict__ cstate, float* __restrict__ out, int t)
{
  __shared__ __align__(16) char smem[38016];   /* 4 rows * 66 cells * 144 B */
  const int tid = threadIdx.x;
  const int w = tid >> 6, lane = tid & 63;
  const int l15 = lane & 15, l4 = lane >> 4;
  const int bid = blockIdx.x;
  const int og = bid & 3, rp = (bid >> 2) & 31, n = bid >> 7;
  const int wr = w >> 1, ch = w & 1;

  const char* gb0 = bnxp   + (size_t)(t*4+n)*IMG_BYTES + rp*16896;
  const char* gb1 = cpad_s + (size_t)n*IMG_BYTES + rp*16896;
  const char* gb2 = hpad_s + (size_t)n*IMG_BYTES + rp*16896;

  f32x4 acc[3][2];
  #pragma unroll
  for (int a = 0; a < 3; ++a)
    #pragma unroll
    for (int b = 0; b < 2; ++b)
      acc[a][b] = (f32x4){0.f,0.f,0.f,0.f};

  const int colbase = ch << 5;
  const int aoff0 = (og << 10) + lane*16;

  for (int j = 0; j < 3; ++j){
    const char* gbj = (j==0) ? gb0 : ((j==1) ? gb1 : gb2);
    if (j) __syncthreads();
    for (int i = tid; i < 2112; i += 256){
      int rr = i / 528, iw = i % 528;
      *(uint4*)(smem + rr*9504 + (iw>>3)*144 + ((iw&7)<<4)) =
          *(const uint4*)(gbj + rr*8448 + (iw<<4));
    }
    __syncthreads();

    const char* wj = wA + j*221184 + aoff0;
    #pragma unroll
    for (int kh = 0; kh < 3; ++kh){
      const char* brow = smem + (wr + kh)*9504 + l4*16;
      #pragma unroll
      for (int kw = 0; kw < 3; ++kw){
        #pragma unroll
        for (int cc = 0; cc < 2; ++cc){
          const char* ab = wj + ((kh*3+kw)*2 + cc)*12288;
          short8 a0 = *(const short8*)(ab);            /* f-gate frag */
          short8 a1 = *(const short8*)(ab + 4096);     /* o-gate frag */
          short8 a2 = *(const short8*)(ab + 8192);     /* g-gate frag */
          const char* bb = brow + (kw + colbase + l15)*144 + (cc<<6);
          #pragma unroll
          for (int cf = 0; cf < 2; ++cf){
            short8 bf = *(const short8*)(bb + cf*2304);
            acc[0][cf] = __builtin_amdgcn_mfma_f32_16x16x32_bf16(a0, bf, acc[0][cf], 0,0,0);
            acc[1][cf] = __builtin_amdgcn_mfma_f32_16x16x32_bf16(a1, bf, acc[1][cf], 0,0,0);
            acc[2][cf] = __builtin_amdgcn_mfma_f32_16x16x32_bf16(a2, bf, acc[2][cf], 0,0,0);
          }
        }
      }
    }
  }

  /* epilogue: gates in-register for this wave's 16 och x 32 positions */
  const int r = (rp << 1) + wr;
  const size_t cb = ((size_t)(n*64)) << 12;
  const size_t ob = ((size_t)((t*4+n)*64)) << 12;
  const int gc0 = (og << 4) + l4*4;
  char* hrow = hpad_d + (size_t)n*IMG_BYTES + (size_t)(r+1)*8448;
  char* crow = cpad_d + (size_t)n*IMG_BYTES + (size_t)(r+1)*8448;

  #pragma unroll
  for (int cf = 0; cf < 2; ++cf){
    const int col = colbase + (cf<<4) + l15;
    const int p = (r<<6) + col;
    union { u16 u[4]; uint2 v; } hp, cp2;
    #pragma unroll
    for (int reg = 0; reg < 4; ++reg){
      const int gc = gc0 + reg;
      float fv = acc[0][cf][reg] + b1[gc];
      float ov = acc[1][cf][reg] + b1[64+gc];
      float gv = acc[2][cf][reg] + b1[128+gc];
      float f  = sigm(fv);
      float og_ = sigm(ov);
      float g  = tanh_(gv);
      float* cptr = cstate + cb + (((size_t)gc)<<12) + p;
      float cprev = *cptr;
      float cn = f*cprev + (1.f-f)*g;
      float hn = og_ * tanh_(cn);
      *cptr = cn;
      out[ob + (((size_t)gc)<<12) + p] = hn;
      hp.u[reg]  = f2b(hn);
      cp2.u[reg] = f2b(cn);
    }
    *(uint2*)(hrow + (size_t)(col+1)*128 + gc0*2) = hp.v;
    *(uint2*)(crow + (size_t)(col+1)*128 + gc0*2) = cp2.v;
  }
}

extern "C" void kernel_launch(void* const* d_in, const int* in_sizes, int n_in,
                              void* d_out, int out_size, void* d_ws, size_t ws_size,
                              hipStream_t stream)
{
  (void)in_sizes; (void)n_in; (void)out_size; (void)ws_size;
  const float* x     = (const float*)d_in[0];
  const float* gamma = (const float*)d_in[1];
  const float* beta  = (const float*)d_in[2];
  const float* c1w   = (const float*)d_in[3];
  const float* c1b   = (const float*)d_in[4];
  const float* wh2h  = (const float*)d_in[5];
  const float* wc2h  = (const float*)d_in[6];
  char* ws  = (char*)d_ws;
  float* out = (float*)d_out;

  char* hpad0 = ws + WS_HC;
  char* cpad0 = ws + WS_HC + (size_t)4*IMG_BYTES;
  char* hpad1 = ws + WS_HC + (size_t)8*IMG_BYTES;
  char* cpad1 = ws + WS_HC + (size_t)12*IMG_BYTES;

  /* zero h/c ping-pong (incl. halos) + c state each call (graph-safe).
     bnxp halos are written by k_bnx itself. */
  hipMemsetAsync(ws + WS_HC, 0, (size_t)16*IMG_BYTES, stream);
  hipMemsetAsync(ws + WS_CSTATE, 0, (size_t)4*64*4096*4, stream);

  k_wt<<<1296, 256, 0, stream>>>(c1w, wc2h, wh2h, (u16*)(ws + WS_WA));
  k_bnsum<<<1024, 256, 0, stream>>>(x, (float*)(ws + WS_PART));
  k_bnfin<<<1, 64, 0, stream>>>((const float*)(ws + WS_PART), gamma, beta,
                                (float*)(ws + WS_SCALE), (float*)(ws + WS_SHIFT));
  k_bnx<<<4224, 256, 0, stream>>>(x, (const float*)(ws + WS_SCALE),
                                  (const float*)(ws + WS_SHIFT), ws + WS_BNXP);
  for (int t = 0; t < 16; ++t){
    const char* cs = (t & 1) ? cpad1 : cpad0;
    const char* hs = (t & 1) ? hpad1 : hpad0;
    char* cd = (t & 1) ? cpad0 : cpad1;
    char* hd = (t & 1) ? hpad0 : hpad1;
    k_step<<<512, 256, 0, stream>>>(ws + WS_BNXP, cs, hs, cd, hd,
                                    ws + WS_WA, c1b,
                                    (float*)(ws + WS_CSTATE), out, t);
  }
}

// Round 6
// 389.751 us; speedup vs baseline: 1.4383x; 1.4383x over previous
//
#include <hip/hip_runtime.h>

typedef unsigned short u16;
typedef unsigned int   u32;
typedef __attribute__((ext_vector_type(8))) short short8;
typedef __attribute__((ext_vector_type(4))) float f32x4;

typedef __attribute__((address_space(1))) const void GASV;
typedef __attribute__((address_space(3))) void LASV;

#define IMG_BYTES  557568      /* 66*66*64*2 (padded bf16 image) */
#define WS_SCALE   0
#define WS_SHIFT   256
#define WS_PART    512         /* 16 groups * 128 floats = 8192 B */
#define WS_WA      8704        /* 27 stages * 24576 B = 663552 B */
#define WS_BNXP    672256      /* 64 * IMG_BYTES */
#define WS_HC      (WS_BNXP + 64*IMG_BYTES)          /* 4 buffers x 4*IMG_BYTES */
#define WS_CSTATE  (WS_HC + 16*IMG_BYTES)            /* 4*64*4096 f32 = 4 MiB */

/* dynamic LDS layout for k_step */
#define SM_IN(j)   ((j)*28512)                /* 3 inputs: 3 rows * 66 * 144 B */
#define SM_WB(b)   (85536 + (b)*24576)        /* 3-deep weight ring */
#define SMEM_TOT   159264

__device__ __forceinline__ u16 f2b(float f){
  u32 x = __float_as_uint(f);
  return (u16)((x + 0x7fffu + ((x>>16)&1u)) >> 16);
}
__device__ __forceinline__ float sigm(float x){ return 1.f/(1.f+__expf(-x)); }
__device__ __forceinline__ float tanh_(float x){
  float e = __expf(2.f*fabsf(x));
  float t = 1.f - 2.f/(e+1.f);      /* inf-safe -> 1 */
  return copysignf(t, x);
}

/* ---- weight transform: f32 [O][C][3][3] -> stage-contiguous bf16 ----
   u16 idx = stage*12288 + cc*6144 + f*512 + lane*8 + e
   stage = j*9 + kh*3 + kw ; f = gate*4 + og
   element = w_j[och = gate*64 + og*16 + (lane&15)][c = cc*32 + (lane>>4)*8 + e] */
__global__ void k_wt(const float* __restrict__ c1, const float* __restrict__ c2h,
                     const float* __restrict__ h2h, u16* __restrict__ wA){
  int idx = blockIdx.x*256 + threadIdx.x;   /* 1296*256 = 331776 exact */
  int e = idx & 7;
  int lane = (idx >> 3) & 63;
  int v = idx >> 9;
  int f = v % 12;  v /= 12;
  int cc = v & 1;  v >>= 1;
  int stage = v;                 /* 0..26 */
  int j = stage / 9, tap = stage % 9;
  int gate = f >> 2, og = f & 3;
  int och = gate*64 + og*16 + (lane & 15);
  int c = cc*32 + (lane >> 4)*8 + e;
  const float* src = (j==0) ? c1 : ((j==1) ? c2h : h2h);
  wA[idx] = f2b(src[(och*64 + c)*9 + tap]);
}

/* ---- BN partial sums: block (c, g) reduces imgs g*4..g*4+3 (f32 input) ---- */
__global__ void k_bnsum(const float* __restrict__ x, float* __restrict__ part){
  int c = blockIdx.x & 63, g = blockIdx.x >> 6;
  int tid = threadIdx.x, w = tid >> 6, lane = tid & 63;
  float s = 0.f, s2 = 0.f;
  for (int im = 0; im < 4; ++im){
    const float* base = x + (((size_t)((g*4+im)*64 + c)) << 12);
    #pragma unroll
    for (int it = 0; it < 4; ++it){
      float4 v = *(const float4*)(base + (((it<<8) + tid) << 2));
      s  += v.x + v.y + v.z + v.w;
      s2 += v.x*v.x + v.y*v.y + v.z*v.z + v.w*v.w;
    }
  }
  #pragma unroll
  for (int off = 32; off > 0; off >>= 1){
    s  += __shfl_down(s,  off);
    s2 += __shfl_down(s2, off);
  }
  __shared__ float red[8];
  if (lane == 0){ red[w] = s; red[4+w] = s2; }
  __syncthreads();
  if (tid == 0){
    float S  = red[0]+red[1]+red[2]+red[3];
    float S2 = red[4]+red[5]+red[6]+red[7];
    part[(g<<7) + c] = S;
    part[(g<<7) + 64 + c] = S2;
  }
}

/* ---- BN finalize: scale/shift per channel (f32 gamma/beta) ---- */
__global__ void k_bnfin(const float* __restrict__ part, const float* __restrict__ gamma,
                        const float* __restrict__ beta, float* __restrict__ scale,
                        float* __restrict__ shift){
  int c = threadIdx.x;
  float S = 0.f, S2 = 0.f;
  for (int g = 0; g < 16; ++g){ S += part[(g<<7)+c]; S2 += part[(g<<7)+64+c]; }
  const float inv = 1.f/262144.f;
  float mean = S*inv;
  float var  = S2*inv - mean*mean;
  float sc = gamma[c] * rsqrtf(var + 1e-5f);
  scale[c] = sc;
  shift[c] = beta[c] - mean*sc;
}

/* ---- BN apply + transpose f32 NCHW -> padded bf16 [img][66][66][64];
        writes halo rows/cols itself (no memset needed). grid 64*66 ---- */
__global__ void k_bnx(const float* __restrict__ x, const float* __restrict__ scale,
                      const float* __restrict__ shift, char* __restrict__ bnxp){
  int img = blockIdx.x / 66, rp = blockIdx.x % 66;
  int tid = threadIdx.x;
  char* dstrow = bnxp + (size_t)img*IMG_BYTES + (size_t)rp*8448;
  const uint4 z = {0,0,0,0};
  if (rp == 0 || rp == 65){
    for (int i = tid; i < 528; i += 256) ((uint4*)dstrow)[i] = z;
    return;
  }
  if (tid < 16)
    *(uint4*)(dstrow + (tid>>3)*(65*128) + (tid&7)*16) = z;   /* halo cols 0,65 */
  int r = rp - 1;
  int col = tid & 63, cq = tid >> 6;
  const float* xb = x + (((size_t)(img*64 + cq*16)) << 12) + (r<<6) + col;
  union { u16 u[16]; uint4 v[2]; } pk;
  #pragma unroll
  for (int i = 0; i < 16; ++i){
    int c = cq*16 + i;
    float vv = xb[((size_t)i) << 12];
    pk.u[i] = f2b(vv*scale[c] + shift[c]);
  }
  char* dst = dstrow + (size_t)(col + 1)*128 + cq*32;
  *(uint4*)dst = pk.v[0];
  *(uint4*)(dst+16) = pk.v[1];
}

/* ---- fused ConvLSTM step: 256 blocks = (img n, row). 512 thr = 8 waves;
        wave (og, ch): 16 och x {f,o,g} x 32 positions. Weights staged
        through a 3-deep LDS ring via global_load_lds, counted vmcnt. ---- */
#define STAGE_W(s, b) do {                                                      \
  const char* _gs = wA + (size_t)(s)*24576 + (w*3)*1024 + lane*16;              \
  char* _ls = smem + SM_WB(b) + (w*3)*1024;                                     \
  __builtin_amdgcn_global_load_lds((GASV*)(_gs),        (LASV*)(_ls),        16, 0, 0); \
  __builtin_amdgcn_global_load_lds((GASV*)(_gs + 1024), (LASV*)(_ls + 1024), 16, 0, 0); \
  __builtin_amdgcn_global_load_lds((GASV*)(_gs + 2048), (LASV*)(_ls + 2048), 16, 0, 0); \
} while(0)

__global__ __launch_bounds__(512, 1) void k_step(
    const char* __restrict__ bnxp,
    const char* __restrict__ cpad_s, const char* __restrict__ hpad_s,
    char* __restrict__ cpad_d, char* __restrict__ hpad_d,
    const char* __restrict__ wA, const float* __restrict__ b1,
    float* __restrict__ cstate, float* __restrict__ out, int t)
{
  extern __shared__ __align__(16) char smem[];
  const int tid = threadIdx.x;
  const int w = tid >> 6, lane = tid & 63;
  const int l15 = lane & 15, l4 = lane >> 4;
  const int og = w >> 1, ch = w & 1;
  const int n = blockIdx.x >> 6, row = blockIdx.x & 63;

  const char* gb0 = bnxp   + (size_t)(t*4+n)*IMG_BYTES + row*8448;
  const char* gb1 = cpad_s + (size_t)n*IMG_BYTES + row*8448;
  const char* gb2 = hpad_s + (size_t)n*IMG_BYTES + row*8448;

  f32x4 acc[3][2];
  #pragma unroll
  for (int a = 0; a < 3; ++a)
    #pragma unroll
    for (int b = 0; b < 2; ++b)
      acc[a][b] = (f32x4){0.f,0.f,0.f,0.f};

  /* prologue: issue weight stages 0,1 asynchronously */
  STAGE_W(0, 0);
  STAGE_W(1, 1);

  /* stage the three input tiles (3 rows x 66 cells x 128B -> 144B cells) */
  #pragma unroll
  for (int j = 0; j < 3; ++j){
    const char* gbj = (j==0) ? gb0 : ((j==1) ? gb1 : gb2);
    char* dj = smem + SM_IN(j);
    #pragma unroll
    for (int rr = 0; rr < 3; ++rr){
      for (int i = tid; i < 528; i += 512)
        *(uint4*)(dj + rr*9504 + (i>>3)*144 + (i&7)*16) =
            *(const uint4*)(gbj + rr*8448 + i*16);
    }
  }
  __syncthreads();   /* drains vmcnt(0): stages 0,1 + inputs all resident */

  #pragma unroll
  for (int j = 0; j < 3; ++j){
    #pragma unroll
    for (int kh = 0; kh < 3; ++kh){
      #pragma unroll
      for (int kw = 0; kw < 3; ++kw){
        const int s = j*9 + kh*3 + kw;
        if (s < 25) STAGE_W(s+2, (s+2)%3);
        {
          const char* ab = smem + SM_WB(s%3) + og*1024 + lane*16;
          const char* ib = smem + SM_IN(j) + kh*9504 + ((ch<<5) + kw + l15)*144 + l4*16;
          #pragma unroll
          for (int cc = 0; cc < 2; ++cc){
            short8 af = *(const short8*)(ab + cc*12288);
            short8 ao = *(const short8*)(ab + cc*12288 + 4096);
            short8 ag = *(const short8*)(ab + cc*12288 + 8192);
            #pragma unroll
            for (int cf = 0; cf < 2; ++cf){
              short8 bf = *(const short8*)(ib + cc*64 + cf*2304);
              acc[0][cf] = __builtin_amdgcn_mfma_f32_16x16x32_bf16(af, bf, acc[0][cf], 0,0,0);
              acc[1][cf] = __builtin_amdgcn_mfma_f32_16x16x32_bf16(ao, bf, acc[1][cf], 0,0,0);
              acc[2][cf] = __builtin_amdgcn_mfma_f32_16x16x32_bf16(ag, bf, acc[2][cf], 0,0,0);
            }
          }
        }
        if (s < 26){
          if (s == 25) asm volatile("s_waitcnt vmcnt(0)" ::: "memory");
          else         asm volatile("s_waitcnt vmcnt(3)" ::: "memory");
          __builtin_amdgcn_s_barrier();
        }
      }
    }
  }

  /* epilogue: gates in-register for this wave's 16 och x 32 positions */
  const size_t cb = ((size_t)(n*64)) << 12;
  const size_t ob = ((size_t)((t*4+n)*64)) << 12;
  const int gc0 = (og << 4) + l4*4;
  char* hrow = hpad_d + (size_t)n*IMG_BYTES + (size_t)(row+1)*8448;
  char* crow = cpad_d + (size_t)n*IMG_BYTES + (size_t)(row+1)*8448;

  #pragma unroll
  for (int cf = 0; cf < 2; ++cf){
    const int col = (ch<<5) + (cf<<4) + l15;
    const int p = (row<<6) + col;
    union { u16 u[4]; uint2 v; } hp, cp2;
    #pragma unroll
    for (int reg = 0; reg < 4; ++reg){
      const int gc = gc0 + reg;
      float fv = acc[0][cf][reg] + b1[gc];
      float ov = acc[1][cf][reg] + b1[64+gc];
      float gv = acc[2][cf][reg] + b1[128+gc];
      float f  = sigm(fv);
      float og_ = sigm(ov);
      float g  = tanh_(gv);
      float* cptr = cstate + cb + (((size_t)gc)<<12) + p;
      float cprev = *cptr;
      float cn = f*cprev + (1.f-f)*g;
      float hn = og_ * tanh_(cn);
      *cptr = cn;
      out[ob + (((size_t)gc)<<12) + p] = hn;
      hp.u[reg]  = f2b(hn);
      cp2.u[reg] = f2b(cn);
    }
    *(uint2*)(hrow + (size_t)(col+1)*128 + gc0*2) = hp.v;
    *(uint2*)(crow + (size_t)(col+1)*128 + gc0*2) = cp2.v;
  }
}

extern "C" void kernel_launch(void* const* d_in, const int* in_sizes, int n_in,
                              void* d_out, int out_size, void* d_ws, size_t ws_size,
                              hipStream_t stream)
{
  (void)in_sizes; (void)n_in; (void)out_size; (void)ws_size;
  const float* x     = (const float*)d_in[0];
  const float* gamma = (const float*)d_in[1];
  const float* beta  = (const float*)d_in[2];
  const float* c1w   = (const float*)d_in[3];
  const float* c1b   = (const float*)d_in[4];
  const float* wh2h  = (const float*)d_in[5];
  const float* wc2h  = (const float*)d_in[6];
  char* ws  = (char*)d_ws;
  float* out = (float*)d_out;

  static int attr_done = 0;
  if (!attr_done){
    hipFuncSetAttribute(reinterpret_cast<const void*>(k_step),
                        hipFuncAttributeMaxDynamicSharedMemorySize, SMEM_TOT);
    attr_done = 1;
  }

  char* hpad0 = ws + WS_HC;
  char* cpad0 = ws + WS_HC + (size_t)4*IMG_BYTES;
  char* hpad1 = ws + WS_HC + (size_t)8*IMG_BYTES;
  char* cpad1 = ws + WS_HC + (size_t)12*IMG_BYTES;

  /* zero h/c ping-pong (incl. halos) + c state each call (graph-safe).
     bnxp halos are written by k_bnx itself. */
  hipMemsetAsync(ws + WS_HC, 0, (size_t)16*IMG_BYTES, stream);
  hipMemsetAsync(ws + WS_CSTATE, 0, (size_t)4*64*4096*4, stream);

  k_wt<<<1296, 256, 0, stream>>>(c1w, wc2h, wh2h, (u16*)(ws + WS_WA));
  k_bnsum<<<1024, 256, 0, stream>>>(x, (float*)(ws + WS_PART));
  k_bnfin<<<1, 64, 0, stream>>>((const float*)(ws + WS_PART), gamma, beta,
                                (float*)(ws + WS_SCALE), (float*)(ws + WS_SHIFT));
  k_bnx<<<4224, 256, 0, stream>>>(x, (const float*)(ws + WS_SCALE),
                                  (const float*)(ws + WS_SHIFT), ws + WS_BNXP);
  for (int t = 0; t < 16; ++t){
    const char* cs = (t & 1) ? cpad1 : cpad0;
    const char* hs = (t & 1) ? hpad1 : hpad0;
    char* cd = (t & 1) ? cpad0 : cpad1;
    char* hd = (t & 1) ? hpad0 : hpad1;
    k_step<<<256, 512, SMEM_TOT, stream>>>(ws + WS_BNXP, cs, hs, cd, hd,
                                           ws + WS_WA, c1b,
                                           (float*)(ws + WS_CSTATE), out, t);
  }
}